// Round 6
// baseline (397.232 us; speedup 1.0000x reference)
//
#include <hip/hip_runtime.h>

#define NN1 32768
#define NE  262144
#define FDIM 256
#define NHEADS 4
#define HIDC 64
#define IN_DIM 128
#define NB 32
#define KK1 512
#define NN2 16384   // NB*KK1
#define KK2 256
#define NN3 8192    // NB*KK2
#define OUT_DIM 256
#define BN_EPS 1e-5f
#define NEG_SLOPE 0.2f

typedef _Float16 half8 __attribute__((ext_vector_type(8)));
typedef _Float16 half4v __attribute__((ext_vector_type(4)));
typedef float floatx4 __attribute__((ext_vector_type(4)));

__device__ __forceinline__ float lrelu(float x) { return x >= 0.f ? x : NEG_SLOPE * x; }
__device__ __forceinline__ float gelu(float v) {
  return 0.5f * v * (1.0f + erff(v * 0.7071067811865476f));
}

// ---------- fused init: x->fp16, W1^T, W2^T, zero deg1/deg2/inv1/bnstats ----------
__global__ void init_k(const float4* __restrict__ x, half4v* __restrict__ ah,
                       const float* __restrict__ W1, _Float16* __restrict__ bt1,
                       const float* __restrict__ W2, _Float16* __restrict__ bt2,
                       int* __restrict__ deg1, int* __restrict__ deg2,
                       int* __restrict__ inv1, float* __restrict__ bnst) {
  int blk = blockIdx.x, tid = threadIdx.x;
  if (blk < 4096) {                       // x fp32 -> fp16 (NN1*128 elems)
    int i = blk * 256 + tid;
    float4 v = x[i];
    half4v h;
    h[0] = (_Float16)v.x; h[1] = (_Float16)v.y; h[2] = (_Float16)v.z; h[3] = (_Float16)v.w;
    ah[i] = h;
  } else if (blk < 4224) {                // W1[128][256] -> bt1[256][128]
    int idx = (blk - 4096) * 256 + tid;
    int n = idx >> 7, k = idx & 127;
    bt1[idx] = (_Float16)W1[k * FDIM + n];
  } else if (blk < 4480) {                // W2[256][256] -> bt2[256][256]
    int idx = (blk - 4224) * 256 + tid;
    int n = idx >> 8, k = idx & 255;
    bt2[idx] = (_Float16)W2[k * FDIM + n];
  } else {                                // zero accumulators
    int i = (blk - 4480) * 256 + tid;
    deg1[i] = 0;
    inv1[i] = -1;
    if (i < NN2) deg2[i] = 0;
    if (i < 1024) bnst[i] = 0.f;
  }
}

// ---------------- MFMA fp16 GEMM: C[M,N](fp16) = A[M,K] * BT[N,K]^T
template <int K>
__global__ void gemm_f16(const _Float16* __restrict__ A, const _Float16* __restrict__ BT,
                         _Float16* __restrict__ C, int N) {
  __shared__ _Float16 As[64 * 40];
  __shared__ _Float16 Bs[128 * 40];
  int tid = threadIdx.x;
  int lane = tid & 63, w = tid >> 6;
  int bm = blockIdx.y * 64, bn = blockIdx.x * 128;
  int wm = (w & 1) * 32, wn = (w >> 1) * 64;
  floatx4 acc[2][4] = {};
  int ar = tid >> 2, ac = (tid & 3) * 8;
  int br = tid >> 1, bc = (tid & 1) * 16;
  int fm = lane & 15, fq = (lane >> 4) * 8;
  for (int k0 = 0; k0 < K; k0 += 32) {
    __syncthreads();
    *(half8*)&As[ar * 40 + ac] = *(const half8*)&A[(size_t)(bm + ar) * K + k0 + ac];
    *(half8*)&Bs[br * 40 + bc] = *(const half8*)&BT[(size_t)(bn + br) * K + k0 + bc];
    *(half8*)&Bs[br * 40 + bc + 8] = *(const half8*)&BT[(size_t)(bn + br) * K + k0 + bc + 8];
    __syncthreads();
    half8 af[2], bf[4];
#pragma unroll
    for (int mt = 0; mt < 2; ++mt)
      af[mt] = *(const half8*)&As[(wm + mt * 16 + fm) * 40 + fq];
#pragma unroll
    for (int nt = 0; nt < 4; ++nt)
      bf[nt] = *(const half8*)&Bs[(wn + nt * 16 + fm) * 40 + fq];
#pragma unroll
    for (int mt = 0; mt < 2; ++mt)
#pragma unroll
      for (int nt = 0; nt < 4; ++nt)
        acc[mt][nt] = __builtin_amdgcn_mfma_f32_16x16x32_f16(af[mt], bf[nt], acc[mt][nt], 0, 0, 0);
  }
  int row0 = bm + wm + (lane >> 4) * 4;
  int col0 = bn + wn + (lane & 15);
#pragma unroll
  for (int mt = 0; mt < 2; ++mt)
#pragma unroll
    for (int nt = 0; nt < 4; ++nt) {
      _Float16* cp = C + (size_t)(row0 + mt * 16) * N + col0 + nt * 16;
#pragma unroll
      for (int i = 0; i < 4; ++i) cp[(size_t)i * N] = (_Float16)acc[mt][nt][i];
    }
}

// attn coefficients (1 wave/node, half4 loads) + optional deg-count ride-along blocks
__global__ void attn_deg_k(const _Float16* __restrict__ h, const float* __restrict__ a_s,
                           const float* __restrict__ a_d, float* __restrict__ asn,
                           float* __restrict__ adn, int n,
                           const int* __restrict__ dstp, int* __restrict__ deg, int ne) {
  int nb = n >> 2;
  if ((int)blockIdx.x < nb) {
    int node = blockIdx.x * 4 + (threadIdx.x >> 6);
    int lane = threadIdx.x & 63, c0 = lane * 4;
    float2 raw = *(const float2*)(h + (size_t)node * FDIM + c0);
    const _Float16* hh = (const _Float16*)&raw;
    float ps = 0.f, pd = 0.f;
#pragma unroll
    for (int j = 0; j < 4; ++j) {
      float hv = (float)hh[j];
      ps = fmaf(hv, a_s[c0 + j], ps);
      pd = fmaf(hv, a_d[c0 + j], pd);
    }
#pragma unroll
    for (int off = 1; off < 16; off <<= 1) {
      ps += __shfl_xor(ps, off);
      pd += __shfl_xor(pd, off);
    }
    if ((lane & 15) == 0) {
      int hd = lane >> 4;
      asn[node * NHEADS + hd] = ps;
      adn[node * NHEADS + hd] = pd;
    }
  } else if (dstp) {
    int e = (blockIdx.x - nb) * 256 + threadIdx.x;
    if (e < ne) {
      int dd = dstp[e];
      if (dd >= 0) atomicAdd(&deg[dd], 1);
    }
  }
}

// 2-level exclusive scan of (deg+1)  (+1 = self loop)
__global__ void exscan1_k(const int* __restrict__ in, int* __restrict__ outv,
                          int* __restrict__ bsum) {
  __shared__ int wsum[16];
  int tid = threadIdx.x, lane = tid & 63, wv = tid >> 6;
  int base = blockIdx.x * 1024;
  int v = in[base + tid] + 1;
  int x = v;
#pragma unroll
  for (int off = 1; off < 64; off <<= 1) {
    int t = __shfl_up(x, off);
    if (lane >= off) x += t;
  }
  if (lane == 63) wsum[wv] = x;
  __syncthreads();
  int woff = 0;
  for (int i = 0; i < wv; i++) woff += wsum[i];
  outv[base + tid] = woff + x - v;
  if (tid == 1023) bsum[blockIdx.x] = woff + x;
}

__global__ void exscan2_k(const int* __restrict__ outv, const int* __restrict__ bsum,
                          int* __restrict__ rowstart, int* __restrict__ cursor,
                          int nblocks, int n) {
  __shared__ int goff;
  int b = blockIdx.x, tid = threadIdx.x;
  if (tid == 0) {
    int s = 0;
    for (int i = 0; i < b; i++) s += bsum[i];
    goff = s;
    if (b == nblocks - 1) rowstart[n] = s + bsum[b];
  }
  __syncthreads();
  int val = outv[b * 1024 + tid] + goff;
  rowstart[b * 1024 + tid] = val;
  cursor[b * 1024 + tid] = val;
}

// CSR fill (real edges + self loops) + per-edge exp(lrelu(asn[s]+adn[d]))
__global__ void csr_fill_p_k(const int* __restrict__ src, const int* __restrict__ dst,
                             int* __restrict__ cursor, const float4* __restrict__ asn4,
                             const float4* __restrict__ adn4, int* __restrict__ csrc,
                             float4* __restrict__ pexp, int ne) {
  int e = blockIdx.x * 256 + threadIdx.x;
  int s, d;
  if (e < ne) {
    d = dst[e];
    if (d < 0) return;
    s = src[e];
  } else {
    s = d = e - ne;   // self loop (grid sized ne+n exactly)
  }
  int pos = atomicAdd(&cursor[d], 1);
  csrc[pos] = s;
  float4 a = asn4[s], b = adn4[d];
  float4 p;
  p.x = expf(lrelu(a.x + b.x));
  p.y = expf(lrelu(a.y + b.y));
  p.z = expf(lrelu(a.z + b.z));
  p.w = expf(lrelu(a.w + b.w));
  pexp[pos] = p;
}

// one wave/node; 2 edges per iteration via half-waves; dwordx4 h loads; fp16+GELU out
__global__ void gat_agg_k(const _Float16* __restrict__ h, const int* __restrict__ rowstart,
                          const int* __restrict__ csrc, const float* __restrict__ pexpf,
                          const float* __restrict__ bias, _Float16* __restrict__ out) {
  int tid = threadIdx.x, lane = tid & 63;
  int hw = lane >> 5, l = lane & 31;
  int d = blockIdx.x * 4 + (tid >> 6);
  int beg = rowstart[d], end = rowstart[d + 1];
  int c0 = l * 8, head = l >> 3;
  float acc[8] = {0.f, 0.f, 0.f, 0.f, 0.f, 0.f, 0.f, 0.f};
  float de = 0.f;
  for (int i = beg; i < end; i += 2) {
    int e0 = i + hw;
    bool valid = e0 < end;
    int s = valid ? csrc[e0] : 0;
    float pw = valid ? pexpf[e0 * 4 + head] : 0.f;
    float4 hv4 = *(const float4*)(h + (size_t)s * FDIM + c0);
    const _Float16* hh = (const _Float16*)&hv4;
    de += pw;
#pragma unroll
    for (int j = 0; j < 8; ++j) acc[j] = fmaf(pw, (float)hh[j], acc[j]);
  }
#pragma unroll
  for (int j = 0; j < 8; ++j) acc[j] += __shfl_xor(acc[j], 32);
  de += __shfl_xor(de, 32);
  if (hw == 0) {
    float inv = 1.f / de;
    _Float16 o[8];
#pragma unroll
    for (int j = 0; j < 8; ++j) o[j] = (_Float16)gelu(acc[j] * inv + bias[c0 + j]);
    *(float4*)(out + (size_t)d * FDIM + c0) = *(const float4*)o;
  }
}

// per-column sum/sumsq partials over fp16 activations
__global__ void stats_k(const _Float16* __restrict__ x, float* __restrict__ sum,
                        float* __restrict__ sumsq, int rows_per_block) {
  int f = threadIdx.x;
  int r0 = blockIdx.x * rows_per_block;
  float s = 0.f, sq = 0.f;
  for (int r = r0; r < r0 + rows_per_block; ++r) {
    float g = (float)x[(size_t)r * FDIM + f];
    s += g;
    sq += g * g;
  }
  atomicAdd(&sum[f], s);
  atomicAdd(&sumsq[f], sq);
}

// score from RAW activations: score = (sum_c x_c*sc_c*w_c + sum_c sh_c*w_c)/||w||
__global__ void score_k(const _Float16* __restrict__ x, const float* __restrict__ bnsum,
                        const float* __restrict__ bnsq, const float* __restrict__ g,
                        const float* __restrict__ be, const float* __restrict__ w,
                        float* __restrict__ score, float inv_n) {
  int gid = blockIdx.x * 256 + threadIdx.x;
  int node = gid >> 6, lane = threadIdx.x & 63;
  int c0 = lane * 4;
  float2 raw = *(const float2*)(x + (size_t)node * FDIM + c0);
  const _Float16* hh = (const _Float16*)&raw;
  float p = 0.f, shw = 0.f, nw = 0.f;
#pragma unroll
  for (int j = 0; j < 4; ++j) {
    int c = c0 + j;
    float mean = bnsum[c] * inv_n;
    float var = bnsq[c] * inv_n - mean * mean;
    float sc = g[c] / sqrtf(var + BN_EPS);
    float sh = be[c] - mean * sc;
    float wv = w[c];
    p = fmaf((float)hh[j], sc * wv, p);
    shw = fmaf(sh, wv, shw);
    nw = fmaf(wv, wv, nw);
  }
#pragma unroll
  for (int off = 32; off > 0; off >>= 1) {
    p += __shfl_xor(p, off);
    shw += __shfl_xor(shw, off);
    nw += __shfl_xor(nw, off);
  }
  if (lane == 0) score[node] = (p + shw) / sqrtf(nw);
}

// rank-selection topk: rank_i = #{j: s_j>s_i or (s_j==s_i and j<i)} — unique, equals sort order
template <int NPG_T, int KEEP>
__global__ void topk_rank_k(const float* __restrict__ score, float* __restrict__ vals,
                            int* __restrict__ gidx, int* __restrict__ inv) {
  __shared__ __align__(16) float sv[NPG_T];
  int tid = threadIdx.x, b = blockIdx.x;
  float v = score[b * NPG_T + tid];
  sv[tid] = v;
  __syncthreads();
  int rank = 0;
  const float4* sv4 = (const float4*)sv;
  for (int j4 = 0; j4 < NPG_T / 4; ++j4) {
    float4 q = sv4[j4];
    int jb = j4 * 4;
    rank += (q.x > v) || (q.x == v && (jb + 0) < tid);
    rank += (q.y > v) || (q.y == v && (jb + 1) < tid);
    rank += (q.z > v) || (q.z == v && (jb + 2) < tid);
    rank += (q.w > v) || (q.w == v && (jb + 3) < tid);
  }
  if (rank < KEEP) {
    int r = b * KEEP + rank;
    vals[r] = v;
    int gg = b * NPG_T + tid;
    gidx[r] = gg;
    if (inv) inv[gg] = r;
  }
}

// pool: gather kept rows, apply BN (deferred) + tanh scale, emit fp16 + readout partials.
// ride-along blocks do the edge remap + layer-2 degree count.
__global__ void pool_remap_k(const _Float16* __restrict__ x, const int* __restrict__ gidx,
                             const float* __restrict__ vals, const float* __restrict__ bnsum,
                             const float* __restrict__ bnsq, const float* __restrict__ g,
                             const float* __restrict__ be, float inv_n,
                             _Float16* __restrict__ ah, float* __restrict__ pmax,
                             float* __restrict__ psum,
                             const int* __restrict__ src, const int* __restrict__ dst,
                             const int* __restrict__ inv, int* __restrict__ ns,
                             int* __restrict__ nd, int* __restrict__ deg2) {
  int f = threadIdx.x;
  if ((int)blockIdx.x < NN2 / 16) {
    int blk = blockIdx.x;
    float mean = bnsum[f] * inv_n;
    float var = bnsq[f] * inv_n - mean * mean;
    float sc = g[f] / sqrtf(var + BN_EPS);
    float sh = be[f] - mean * sc;
    float mx = -3.0e38f, sm = 0.f;
    int r0 = blk * 16;
#pragma unroll 4
    for (int j = 0; j < 16; ++j) {
      int r = r0 + j;
      float t = tanhf(vals[r]);
      float raw = (float)x[(size_t)gidx[r] * FDIM + f];
      float v = fmaf(raw, sc, sh) * t;
      ah[(size_t)r * FDIM + f] = (_Float16)v;
      mx = fmaxf(mx, v);
      sm += v;
    }
    pmax[(size_t)blk * FDIM + f] = mx;
    psum[(size_t)blk * FDIM + f] = sm;
  } else {
    int e = (blockIdx.x - NN2 / 16) * 256 + f;
    if (e < NE) {
      int a = inv[src[e]], bb = inv[dst[e]];
      bool ok = (a >= 0) && (bb >= 0);
      ns[e] = ok ? a : -1;
      nd[e] = ok ? bb : -1;
      if (ok) atomicAdd(&deg2[bb], 1);
    }
  }
}

// layer-2 pool: BN+tanh + partials only
__global__ void pool2_k(const _Float16* __restrict__ x, const int* __restrict__ gidx,
                        const float* __restrict__ vals, const float* __restrict__ bnsum,
                        const float* __restrict__ bnsq, const float* __restrict__ g,
                        const float* __restrict__ be, float inv_n,
                        float* __restrict__ pmax, float* __restrict__ psum) {
  int blk = blockIdx.x, f = threadIdx.x;
  float mean = bnsum[f] * inv_n;
  float var = bnsq[f] * inv_n - mean * mean;
  float sc = g[f] / sqrtf(var + BN_EPS);
  float sh = be[f] - mean * sc;
  float mx = -3.0e38f, sm = 0.f;
  int r0 = blk * 16;
#pragma unroll 4
  for (int j = 0; j < 16; ++j) {
    int r = r0 + j;
    float t = tanhf(vals[r]);
    float raw = (float)x[(size_t)gidx[r] * FDIM + f];
    float v = fmaf(raw, sc, sh) * t;
    mx = fmaxf(mx, v);
    sm += v;
  }
  pmax[(size_t)blk * FDIM + f] = mx;
  psum[(size_t)blk * FDIM + f] = sm;
}

// fused readout-final (both layers) + output linear
__global__ void final_k(const float* __restrict__ pmax1, const float* __restrict__ psum1,
                        const float* __restrict__ pmax2, const float* __restrict__ psum2,
                        const float* __restrict__ Wl, const float* __restrict__ bl,
                        float* __restrict__ out) {
  __shared__ float xs[2 * FDIM];
  int b = blockIdx.x, f = threadIdx.x;
  float mx1 = -3.0e38f, s1 = 0.f, mx2 = -3.0e38f, s2 = 0.f;
  for (int s = 0; s < KK1 / 16; ++s) {
    mx1 = fmaxf(mx1, pmax1[(size_t)(b * (KK1 / 16) + s) * FDIM + f]);
    s1 += psum1[(size_t)(b * (KK1 / 16) + s) * FDIM + f];
  }
  for (int s = 0; s < KK2 / 16; ++s) {
    mx2 = fmaxf(mx2, pmax2[(size_t)(b * (KK2 / 16) + s) * FDIM + f]);
    s2 += psum2[(size_t)(b * (KK2 / 16) + s) * FDIM + f];
  }
  xs[f] = mx1 + mx2;
  xs[FDIM + f] = s1 * (1.0f / KK1) + s2 * (1.0f / KK2);
  __syncthreads();
  float acc = bl[f];
  const float* wp = Wl + (size_t)f * 512;
  for (int j = 0; j < 512; ++j) acc = fmaf(xs[j], wp[j], acc);
  out[b * OUT_DIM + f] = acc;
}

extern "C" void kernel_launch(void* const* d_in, const int* in_sizes, int n_in,
                              void* d_out, int out_size, void* d_ws, size_t ws_size,
                              hipStream_t stream) {
  (void)in_sizes; (void)n_in; (void)out_size; (void)ws_size;
  const float* x   = (const float*)d_in[0];
  const int* eidx  = (const int*)d_in[1];
  const int* src   = eidx;
  const int* dst   = eidx + NE;
  const float* W1  = (const float*)d_in[3];
  const float* as1 = (const float*)d_in[4];
  const float* ad1 = (const float*)d_in[5];
  const float* b1  = (const float*)d_in[6];
  const float* g1  = (const float*)d_in[7];
  const float* be1 = (const float*)d_in[8];
  const float* pw1 = (const float*)d_in[9];
  const float* W2  = (const float*)d_in[10];
  const float* as2 = (const float*)d_in[11];
  const float* ad2 = (const float*)d_in[12];
  const float* b2  = (const float*)d_in[13];
  const float* g2  = (const float*)d_in[14];
  const float* be2 = (const float*)d_in[15];
  const float* pw2 = (const float*)d_in[16];
  const float* Wl  = (const float*)d_in[17];
  const float* bl  = (const float*)d_in[18];
  float* out = (float*)d_out;

  char* wsp = (char*)d_ws;
  size_t off = 0;
  auto alloc = [&](size_t bytes) -> void* {
    void* p = wsp + off;
    off += (bytes + 255) & ~(size_t)255;
    return p;
  };
  _Float16* h16 = (_Float16*)alloc((size_t)NN1 * FDIM * 2);     // fp16 h (both layers)
  _Float16* o16 = (_Float16*)alloc((size_t)NN1 * FDIM * 2);     // fp16 GELU(gat) (both layers)
  _Float16* ah  = (_Float16*)alloc((size_t)NN1 * IN_DIM * 2);   // fp16 GEMM A (both layers)
  _Float16* bt1 = (_Float16*)alloc((size_t)FDIM * IN_DIM * 2);
  _Float16* bt2 = (_Float16*)alloc((size_t)FDIM * FDIM * 2);
  float* asn    = (float*)alloc((size_t)NN1 * NHEADS * 4);
  float* adn    = (float*)alloc((size_t)NN1 * NHEADS * 4);
  float4* pexp  = (float4*)alloc((size_t)(NE + NN1) * 16);
  int*   deg1   = (int*)alloc((size_t)NN1 * 4);
  int*   deg2   = (int*)alloc((size_t)NN2 * 4);
  int*   rowst  = (int*)alloc((size_t)(NN1 + 1) * 4);
  int*   cursor = (int*)alloc((size_t)NN1 * 4);
  int*   scanv  = (int*)alloc((size_t)NN1 * 4);
  int*   bsum   = (int*)alloc(64 * 4);
  int*   csrc   = (int*)alloc((size_t)(NE + NN1) * 4);
  int*   ns     = (int*)alloc((size_t)NE * 4);
  int*   nd     = (int*)alloc((size_t)NE * 4);
  int*   inv1   = (int*)alloc((size_t)NN1 * 4);
  float* score  = (float*)alloc((size_t)NN1 * 4);
  float* vals   = (float*)alloc((size_t)NN2 * 4);
  int*   gidx   = (int*)alloc((size_t)NN2 * 4);
  float* bnst   = (float*)alloc(1024 * 4);   // [bn1sum|bn1sq|bn2sum|bn2sq] x256
  float* pmax1  = (float*)alloc((size_t)(NN2 / 16) * FDIM * 4);
  float* psum1  = (float*)alloc((size_t)(NN2 / 16) * FDIM * 4);
  float* pmax2  = (float*)alloc((size_t)(NN3 / 16) * FDIM * 4);
  float* psum2  = (float*)alloc((size_t)(NN3 / 16) * FDIM * 4);

  // ---------- init ----------
  init_k<<<4608, 256, 0, stream>>>((const float4*)x, (half4v*)ah, W1, bt1, W2, bt2,
                                   deg1, deg2, inv1, bnst);
  // ---------- layer 1 ----------
  gemm_f16<IN_DIM><<<dim3(FDIM / 128, NN1 / 64), 256, 0, stream>>>(ah, bt1, h16, FDIM);
  attn_deg_k<<<NN1 / 4 + NE / 256, 256, 0, stream>>>(h16, as1, ad1, asn, adn, NN1,
                                                     dst, deg1, NE);
  exscan1_k<<<NN1 / 1024, 1024, 0, stream>>>(deg1, scanv, bsum);
  exscan2_k<<<NN1 / 1024, 1024, 0, stream>>>(scanv, bsum, rowst, cursor, NN1 / 1024, NN1);
  csr_fill_p_k<<<(NE + NN1) / 256, 256, 0, stream>>>(src, dst, cursor, (const float4*)asn,
                                                     (const float4*)adn, csrc, pexp, NE);
  gat_agg_k<<<NN1 / 4, 256, 0, stream>>>(h16, rowst, csrc, (const float*)pexp, b1, o16);
  stats_k<<<NN1 / 128, 256, 0, stream>>>(o16, bnst, bnst + 256, 128);
  score_k<<<NN1 / 4, 256, 0, stream>>>(o16, bnst, bnst + 256, g1, be1, pw1, score, 1.0f / NN1);
  topk_rank_k<1024, 512><<<NB, 1024, 0, stream>>>(score, vals, gidx, inv1);
  pool_remap_k<<<NN2 / 16 + NE / 256, 256, 0, stream>>>(o16, gidx, vals, bnst, bnst + 256,
                                                        g1, be1, 1.0f / NN1, ah, pmax1, psum1,
                                                        src, dst, inv1, ns, nd, deg2);
  // ---------- layer 2 ----------
  gemm_f16<FDIM><<<dim3(FDIM / 128, NN2 / 64), 256, 0, stream>>>(ah, bt2, h16, FDIM);
  attn_deg_k<<<NN2 / 4, 256, 0, stream>>>(h16, as2, ad2, asn, adn, NN2, nullptr, nullptr, 0);
  exscan1_k<<<NN2 / 1024, 1024, 0, stream>>>(deg2, scanv, bsum);
  exscan2_k<<<NN2 / 1024, 1024, 0, stream>>>(scanv, bsum, rowst, cursor, NN2 / 1024, NN2);
  csr_fill_p_k<<<(NE + NN2) / 256, 256, 0, stream>>>(ns, nd, cursor, (const float4*)asn,
                                                     (const float4*)adn, csrc, pexp, NE);
  gat_agg_k<<<NN2 / 4, 256, 0, stream>>>(h16, rowst, csrc, (const float*)pexp, b2, o16);
  stats_k<<<NN2 / 128, 256, 0, stream>>>(o16, bnst + 512, bnst + 768, 128);
  score_k<<<NN2 / 4, 256, 0, stream>>>(o16, bnst + 512, bnst + 768, g2, be2, pw2, score,
                                       1.0f / NN2);
  topk_rank_k<512, 256><<<NB, 512, 0, stream>>>(score, vals, gidx, nullptr);
  pool2_k<<<NN3 / 16, 256, 0, stream>>>(o16, gidx, vals, bnst + 512, bnst + 768, g2, be2,
                                        1.0f / NN2, pmax2, psum2);
  // ---------- final ----------
  final_k<<<NB, 256, 0, stream>>>(pmax1, psum1, pmax2, psum2, Wl, bl, out);
}